// Round 6
// baseline (103.247 us; speedup 1.0000x reference)
//
#include <hip/hip_runtime.h>

// hnode_prompt_layer_feature_cat_edge
// out[d, 0:128]   = (sum_{e: dst[e]=d} emb[src[e]]) * w
// out[d, 128:160] =  sum_{e: dst[e]=d} e_feat[e]
//
// R6: bucket CSR (R3/R5) + gather restructured to ONE NODE PER 64-LANE WAVE:
//  - 8 edges/iteration (each 32-lane half handles 4 emb rows; e_feat uses all
//    8 lane-groups) -> 2x outstanding loads vs R5.
//  - nontemporal load/store on single-use streams (e_feat, bucket, out) so L2
//    keeps emb rows (25.6MB table, randomly gathered 307MB logical).
//  - all __shfl convergent: ds_bpermute from exec-inactive source lanes is
//    UNDEFINED; shfls are hoisted out of guards with clamped source index.

#define D_FT 128
#define D_E 32
#define D_OUT (D_FT + D_E)
#define CAP 32

typedef float f32x4 __attribute__((ext_vector_type(4)));
typedef int   i32x2 __attribute__((ext_vector_type(2)));

__global__ void place_bucket_kernel(const int* __restrict__ src_idx,
                                    const int* __restrict__ dst_idx,
                                    int* __restrict__ cursor,
                                    i32x2* __restrict__ bucket,
                                    int* __restrict__ ovf,
                                    int* __restrict__ ovf_cnt, int E) {
    int i = blockIdx.x * blockDim.x + threadIdx.x;
    if (i >= E) return;
    int d = dst_idx[i];
    int slot = atomicAdd(&cursor[d], 1);
    if (slot < CAP) {
        i32x2 pr; pr.x = src_idx[i]; pr.y = i;
        bucket[(size_t)d * CAP + slot] = pr;
    } else {
        int p = atomicAdd(ovf_cnt, 1);
        ovf[p] = i;
    }
}

__global__ void gather_bucket_kernel(const float* __restrict__ emb,
                                     const float* __restrict__ e_feat,
                                     const float* __restrict__ w,
                                     const int* __restrict__ cursor,
                                     const i32x2* __restrict__ bucket,
                                     float* __restrict__ out, int N) {
    int g = (blockIdx.x * blockDim.x + threadIdx.x) >> 6;   // node = one wave
    if (g >= N) return;                                     // wave-uniform exit
    const int lane = threadIdx.x & 63;
    const int half = lane >> 5;      // 0/1: which 4-edge slice of the 8/iter
    const int q    = lane & 31;      // float4 slot within the 128-wide row
    const int qg   = q >> 3;         // e_feat edge-subgroup 0..3 within half
    const int ql   = q & 7;          // float4 slot within e_feat row

    int cnt = cursor[g];
    cnt = cnt > CAP ? CAP : cnt;
    i32x2 pr; pr.x = 0; pr.y = 0;
    if (lane < cnt)
        pr = __builtin_nontemporal_load(&bucket[(size_t)g * CAP + lane]);

    float4 accft = make_float4(0.f, 0.f, 0.f, 0.f);
    float4 acce  = make_float4(0.f, 0.f, 0.f, 0.f);  // partial for (half,qg)

    int i = 0;
    for (; i + 8 <= cnt; i += 8) {
        // convergent shfls: sources b..b+3 < cnt are valid lanes
        int b  = i + (half << 2);
        int s0 = __shfl(pr.x, b + 0, 64);
        int s1 = __shfl(pr.x, b + 1, 64);
        int s2 = __shfl(pr.x, b + 2, 64);
        int s3 = __shfl(pr.x, b + 3, 64);
        int ee = __shfl(pr.y, b + qg, 64);
        float4 v0 = *reinterpret_cast<const float4*>(emb + (size_t)s0 * D_FT + q * 4);
        float4 v1 = *reinterpret_cast<const float4*>(emb + (size_t)s1 * D_FT + q * 4);
        float4 v2 = *reinterpret_cast<const float4*>(emb + (size_t)s2 * D_FT + q * 4);
        float4 v3 = *reinterpret_cast<const float4*>(emb + (size_t)s3 * D_FT + q * 4);
        f32x4 a = __builtin_nontemporal_load(
            reinterpret_cast<const f32x4*>(e_feat + (size_t)ee * D_E + ql * 4));
        accft.x += (v0.x + v1.x) + (v2.x + v3.x);
        accft.y += (v0.y + v1.y) + (v2.y + v3.y);
        accft.z += (v0.z + v1.z) + (v2.z + v3.z);
        accft.w += (v0.w + v1.w) + (v2.w + v3.w);
        acce.x += a.x; acce.y += a.y; acce.z += a.z; acce.w += a.w;
    }
    // e_feat tail: r = cnt - i in [0,7], one shot across 8 lane-groups.
    // shfl OUTSIDE the guard, clamped source (always an active, valid lane).
    {
        int t = i + (half << 2) + qg;
        int tsrc = (t < cnt) ? t : 0;
        int ee = __shfl(pr.y, tsrc, 64);
        if (t < cnt) {
            f32x4 a = __builtin_nontemporal_load(
                reinterpret_cast<const f32x4*>(e_feat + (size_t)ee * D_E + ql * 4));
            acce.x += a.x; acce.y += a.y; acce.z += a.z; acce.w += a.w;
        }
    }
    // emb tail: halves split odd/even; loop bounds uniform, shfl unguarded.
    for (int j = i; j < cnt; j += 2) {
        int t = j + half;
        int tsrc = (t < cnt) ? t : 0;
        int s = __shfl(pr.x, tsrc, 64);
        if (t < cnt) {
            float4 v = *reinterpret_cast<const float4*>(emb + (size_t)s * D_FT + q * 4);
            accft.x += v.x; accft.y += v.y; accft.z += v.z; accft.w += v.w;
        }
    }

    // combine the two halves' ft partials
    accft.x += __shfl_xor(accft.x, 32, 64);
    accft.y += __shfl_xor(accft.y, 32, 64);
    accft.z += __shfl_xor(accft.z, 32, 64);
    accft.w += __shfl_xor(accft.w, 32, 64);
    // combine e partials: across qg (8,16) then across halves (32)
    acce.x += __shfl_xor(acce.x, 8, 64);
    acce.y += __shfl_xor(acce.y, 8, 64);
    acce.z += __shfl_xor(acce.z, 8, 64);
    acce.w += __shfl_xor(acce.w, 8, 64);
    acce.x += __shfl_xor(acce.x, 16, 64);
    acce.y += __shfl_xor(acce.y, 16, 64);
    acce.z += __shfl_xor(acce.z, 16, 64);
    acce.w += __shfl_xor(acce.w, 16, 64);
    acce.x += __shfl_xor(acce.x, 32, 64);
    acce.y += __shfl_xor(acce.y, 32, 64);
    acce.z += __shfl_xor(acce.z, 32, 64);
    acce.w += __shfl_xor(acce.w, 32, 64);

    if (half == 0) {
        float4 wv = *reinterpret_cast<const float4*>(w + q * 4);
        float* o = out + (size_t)g * D_OUT;
        f32x4 r; r.x = accft.x * wv.x; r.y = accft.y * wv.y;
                 r.z = accft.z * wv.z; r.w = accft.w * wv.w;
        __builtin_nontemporal_store(r, reinterpret_cast<f32x4*>(o + q * 4));
        if (q < 8) {
            f32x4 re; re.x = acce.x; re.y = acce.y; re.z = acce.z; re.w = acce.w;
            __builtin_nontemporal_store(re, reinterpret_cast<f32x4*>(o + D_FT + q * 4));
        }
    }
}

// Drain overflow edges (deg > CAP; ~never fires for this data, correct always).
__global__ void ovf_scatter_kernel(const float* __restrict__ emb,
                                   const float* __restrict__ e_feat,
                                   const float* __restrict__ w,
                                   const int* __restrict__ src_idx,
                                   const int* __restrict__ dst_idx,
                                   const int* __restrict__ ovf,
                                   const int* __restrict__ ovf_cnt,
                                   float* __restrict__ out) {
    int n = *ovf_cnt;
    int total = n * 40;   // 32 ft float4-slots + 8 e float4-slots per edge
    for (int t = blockIdx.x * blockDim.x + threadIdx.x; t < total;
         t += gridDim.x * blockDim.x) {
        int e = t / 40, slot = t % 40;
        int eid = ovf[e];
        int d = dst_idx[eid];
        float* o = out + (size_t)d * D_OUT;
        if (slot < 32) {
            int s = src_idx[eid];
            float4 v  = *reinterpret_cast<const float4*>(emb + (size_t)s * D_FT + slot * 4);
            float4 wv = *reinterpret_cast<const float4*>(w + slot * 4);
            atomicAdd(o + slot * 4 + 0, v.x * wv.x);
            atomicAdd(o + slot * 4 + 1, v.y * wv.y);
            atomicAdd(o + slot * 4 + 2, v.z * wv.z);
            atomicAdd(o + slot * 4 + 3, v.w * wv.w);
        } else {
            int qq = slot - 32;
            float4 ve = *reinterpret_cast<const float4*>(e_feat + (size_t)eid * D_E + qq * 4);
            atomicAdd(o + D_FT + qq * 4 + 0, ve.x);
            atomicAdd(o + D_FT + qq * 4 + 1, ve.y);
            atomicAdd(o + D_FT + qq * 4 + 2, ve.z);
            atomicAdd(o + D_FT + qq * 4 + 3, ve.w);
        }
    }
}

// ---- fallback (R1 atomic path) if ws too small ----
__global__ void scatter_ft_kernel(const float* __restrict__ emb, const float* __restrict__ w,
                                  const int* __restrict__ src_idx, const int* __restrict__ dst_idx,
                                  float* __restrict__ out, int n_items) {
    int idx = blockIdx.x * blockDim.x + threadIdx.x;
    if (idx >= n_items) return;
    int e = idx >> 5, q = idx & 31;
    int s = src_idx[e], d = dst_idx[e];
    const float4 v  = *reinterpret_cast<const float4*>(emb + (size_t)s * D_FT + q * 4);
    const float4 wv = *reinterpret_cast<const float4*>(w + q * 4);
    float* o = out + (size_t)d * D_OUT + q * 4;
    atomicAdd(o + 0, v.x * wv.x); atomicAdd(o + 1, v.y * wv.y);
    atomicAdd(o + 2, v.z * wv.z); atomicAdd(o + 3, v.w * wv.w);
}
__global__ void scatter_e_kernel(const float* __restrict__ e_feat, const int* __restrict__ dst_idx,
                                 float* __restrict__ out, int n_items) {
    int idx = blockIdx.x * blockDim.x + threadIdx.x;
    if (idx >= n_items) return;
    int e = idx >> 3, q = idx & 7;
    int d = dst_idx[e];
    const float4 v = *reinterpret_cast<const float4*>(e_feat + (size_t)e * D_E + q * 4);
    float* o = out + (size_t)d * D_OUT + D_FT + q * 4;
    atomicAdd(o + 0, v.x); atomicAdd(o + 1, v.y);
    atomicAdd(o + 2, v.z); atomicAdd(o + 3, v.w);
}

extern "C" void kernel_launch(void* const* d_in, const int* in_sizes, int n_in,
                              void* d_out, int out_size, void* d_ws, size_t ws_size,
                              hipStream_t stream) {
    const float* emb    = (const float*)d_in[0];   // [N, 128]
    const float* e_feat = (const float*)d_in[1];   // [E, 32]
    const float* w      = (const float*)d_in[2];   // [1, 128]
    const int*   src    = (const int*)d_in[3];     // [E]
    const int*   dst    = (const int*)d_in[4];     // [E]
    float* out = (float*)d_out;                    // [N, 160]

    const int E = in_sizes[3];
    const int N = out_size / D_OUT;

    // ws layout: cursor[N] | ovf_cnt[1] | pad[1] | bucket[N*CAP] int2 | ovf[E]
    size_t ints_head = (size_t)N + 2;
    size_t need = ints_head * 4 + (size_t)N * CAP * 8 + (size_t)E * 4;

    if (ws_size >= need) {
        int*   cursor  = (int*)d_ws;
        int*   ovf_cnt = cursor + N;
        i32x2* bucket  = (i32x2*)(cursor + ints_head);
        int*   ovf     = (int*)(bucket + (size_t)N * CAP);

        hipMemsetAsync(cursor, 0, ints_head * sizeof(int), stream);
        place_bucket_kernel<<<(E + 255) / 256, 256, 0, stream>>>(
            src, dst, cursor, bucket, ovf, ovf_cnt, E);
        gather_bucket_kernel<<<((size_t)N * 64 + 255) / 256, 256, 0, stream>>>(
            emb, e_feat, w, cursor, bucket, out, N);
        ovf_scatter_kernel<<<128, 256, 0, stream>>>(
            emb, e_feat, w, src, dst, ovf, ovf_cnt, out);
    } else {
        hipMemsetAsync(d_out, 0, (size_t)out_size * sizeof(float), stream);
        int items_ft = E * 32, items_e = E * 8;
        scatter_ft_kernel<<<(items_ft + 255) / 256, 256, 0, stream>>>(emb, w, src, dst, out, items_ft);
        scatter_e_kernel<<<(items_e + 255) / 256, 256, 0, stream>>>(e_feat, dst, out, items_e);
    }
}